// Round 2
// baseline (802.459 us; speedup 1.0000x reference)
//
#include <hip/hip_runtime.h>
#include <hip/hip_bf16.h>

#define NB 4
#define NT 40000
#define NS0 30000
#define ND0 15000
#define NE0 360000
#define ND1 7500
#define NE1 180000
#define DIN 64
#define D1 64
#define H1 8
#define D2 32
#define NEG 0.2f

// ---------------- init: zero denominators, bias-init accumulators ----------
__global__ void k0_init(float* __restrict__ den1, float* __restrict__ den2,
                        float* __restrict__ agg1, float* __restrict__ outp,
                        const float* __restrict__ b1, const float* __restrict__ b2) {
    int stride = gridDim.x * blockDim.x;
    int i0 = blockIdx.x * blockDim.x + threadIdx.x;
    for (int i = i0; i < NB*ND0*H1; i += stride) den1[i] = 0.f;
    for (int i = i0; i < NB*ND1;    i += stride) den2[i] = 0.f;
    for (int i = i0; i < NB*ND0*D1; i += stride) agg1[i] = b1[i & 63];
    for (int i = i0; i < NB*ND1*D2; i += stride) outp[i] = b2[i & 31];
}

// ---------------- layer 1 node transform: ht1 = x[n_id0] @ W1, es1, ed1 ----
__global__ __launch_bounds__(256) void k1_node1(
        const float* __restrict__ x, const int* __restrict__ n_id0,
        const float* __restrict__ W1, const float* __restrict__ a_src,
        const float* __restrict__ a_dst,
        float* __restrict__ ht1, float* __restrict__ es1, float* __restrict__ ed1) {
    __shared__ float Wl[64*64];
    __shared__ float asl[64], adl[64];
    for (int i = threadIdx.x; i < 64*64; i += 256) Wl[i] = W1[i];
    if (threadIdx.x < 64) { asl[threadIdx.x] = a_src[threadIdx.x]; adl[threadIdx.x] = a_dst[threadIdx.x]; }
    __syncthreads();
    int lane = threadIdx.x & 63;
    int wave = threadIdx.x >> 6;
    int row = blockIdx.x * 4 + wave;          // row in [0, NB*NS0)
    if (row >= NB*NS0) return;
    int b = row / NS0;
    int n = row - b * NS0;
    int id = n_id0[n];
    float xv = x[((size_t)b*NT + id)*DIN + lane];
    float acc = 0.f;
    #pragma unroll
    for (int k = 0; k < 64; ++k) {
        float xk = __shfl(xv, k);
        acc = fmaf(xk, Wl[k*64 + lane], acc);
    }
    ht1[(size_t)row*64 + lane] = acc;
    float vs = acc * asl[lane];
    float vd = acc * adl[lane];
    vs += __shfl_xor(vs, 1); vs += __shfl_xor(vs, 2); vs += __shfl_xor(vs, 4);
    vd += __shfl_xor(vd, 1); vd += __shfl_xor(vd, 2); vd += __shfl_xor(vd, 4);
    if ((lane & 7) == 0) {
        es1[row*8 + (lane >> 3)] = vs;
        ed1[row*8 + (lane >> 3)] = vd;
    }
}

// ---------------- layer 1 softmax denominators ----------------------------
__global__ void k2_den1(const int* __restrict__ esrc, const int* __restrict__ edst,
                        const int* __restrict__ res0,
                        const float* __restrict__ es1, const float* __restrict__ ed1,
                        float* __restrict__ den1) {
    int t = blockIdx.x * blockDim.x + threadIdx.x;   // t = e*32 + b*8 + h
    if (t >= NE0*32) return;
    int e = t >> 5;
    int b = (t >> 3) & 3;
    int h = t & 7;
    int s = esrc[e], d = edst[e];
    int dn = res0[d];
    float logit = es1[(b*NS0 + s)*8 + h] + ed1[(b*NS0 + dn)*8 + h];
    logit = logit > 0.f ? logit : NEG * logit;
    atomicAdd(&den1[(b*ND0 + d)*8 + h], __expf(logit));
}

// ---------------- layer 1 weighted scatter --------------------------------
__global__ void k3_scat1(const int* __restrict__ esrc, const int* __restrict__ edst,
                         const int* __restrict__ res0,
                         const float* __restrict__ es1, const float* __restrict__ ed1,
                         const float* __restrict__ den1, const float* __restrict__ ht1,
                         float* __restrict__ agg1) {
    int t = blockIdx.x * blockDim.x + threadIdx.x;   // t = ((e*4+b)<<6) + ch
    if (t >= NE0*4*64) return;
    int ch = t & 63;
    int b  = (t >> 6) & 3;
    int e  = t >> 8;
    int s = esrc[e], d = edst[e];
    int dn = res0[d];
    int h = ch >> 3;
    float logit = es1[(b*NS0 + s)*8 + h] + ed1[(b*NS0 + dn)*8 + h];
    logit = logit > 0.f ? logit : NEG * logit;
    float alpha = __expf(logit) / den1[(b*ND0 + d)*8 + h];
    float v = alpha * ht1[((size_t)(b*NS0 + s))*64 + ch];
    atomicAdd(&agg1[((size_t)(b*ND0 + d))*64 + ch], v);
}

// ---------------- ELU ------------------------------------------------------
__global__ void k4_elu(float* __restrict__ agg1) {
    int t = blockIdx.x * blockDim.x + threadIdx.x;
    if (t < NB*ND0*D1) {
        float v = agg1[t];
        agg1[t] = v > 0.f ? v : (__expf(v) - 1.f);
    }
}

// ---------------- layer 2 node transform: ht2 = h @ W2, es2, ed2 -----------
__global__ __launch_bounds__(256) void k5_node2(
        const float* __restrict__ h, const float* __restrict__ W2,
        const float* __restrict__ a_src2, const float* __restrict__ a_dst2,
        float* __restrict__ ht2, float* __restrict__ es2, float* __restrict__ ed2) {
    __shared__ float Wl[64*32];
    __shared__ float hl[8][64];
    __shared__ float as2[32], ad2[32];
    for (int i = threadIdx.x; i < 64*32; i += 256) Wl[i] = W2[i];
    if (threadIdx.x < 32) { as2[threadIdx.x] = a_src2[threadIdx.x]; ad2[threadIdx.x] = a_dst2[threadIdx.x]; }
    __syncthreads();
    int base = blockIdx.x * 8;                 // rows total NB*ND0 = 60000 (div by 8)
    for (int i = threadIdx.x; i < 512; i += 256) {
        int r = i >> 6, k = i & 63;
        hl[r][k] = h[(size_t)(base + r)*64 + k];
    }
    __syncthreads();
    int r = threadIdx.x >> 5, c = threadIdx.x & 31;
    float acc = 0.f;
    #pragma unroll
    for (int k = 0; k < 64; ++k) acc = fmaf(hl[r][k], Wl[k*32 + c], acc);
    int row = base + r;
    ht2[(size_t)row*32 + c] = acc;
    float vs = acc * as2[c], vd = acc * ad2[c];
    vs += __shfl_xor(vs, 1); vs += __shfl_xor(vs, 2); vs += __shfl_xor(vs, 4);
    vs += __shfl_xor(vs, 8); vs += __shfl_xor(vs, 16);
    vd += __shfl_xor(vd, 1); vd += __shfl_xor(vd, 2); vd += __shfl_xor(vd, 4);
    vd += __shfl_xor(vd, 8); vd += __shfl_xor(vd, 16);
    if (c == 0) { es2[row] = vs; ed2[row] = vd; }
}

// ---------------- layer 2 softmax denominators ----------------------------
__global__ void k6_den2(const int* __restrict__ esrc, const int* __restrict__ edst,
                        const int* __restrict__ res1,
                        const float* __restrict__ es2, const float* __restrict__ ed2,
                        float* __restrict__ den2) {
    int t = blockIdx.x * blockDim.x + threadIdx.x;   // t = e*4 + b
    if (t >= NE1*4) return;
    int e = t >> 2;
    int b = t & 3;
    int s = esrc[e], d = edst[e];
    int dn = res1[d];
    float logit = es2[b*ND0 + s] + ed2[b*ND0 + dn];
    logit = logit > 0.f ? logit : NEG * logit;
    atomicAdd(&den2[b*ND1 + d], __expf(logit));
}

// ---------------- layer 2 weighted scatter into d_out ---------------------
__global__ void k7_scat2(const int* __restrict__ esrc, const int* __restrict__ edst,
                         const int* __restrict__ res1,
                         const float* __restrict__ es2, const float* __restrict__ ed2,
                         const float* __restrict__ den2, const float* __restrict__ ht2,
                         float* __restrict__ outp) {
    int t = blockIdx.x * blockDim.x + threadIdx.x;   // t = ((e*4+b)<<5) + c
    if (t >= NE1*4*32) return;
    int c = t & 31;
    int b = (t >> 5) & 3;
    int e = t >> 7;
    int s = esrc[e], d = edst[e];
    int dn = res1[d];
    float logit = es2[b*ND0 + s] + ed2[b*ND0 + dn];
    logit = logit > 0.f ? logit : NEG * logit;
    float alpha = __expf(logit) / den2[b*ND1 + d];
    float v = alpha * ht2[(size_t)(b*ND0 + s)*32 + c];
    atomicAdd(&outp[(size_t)(b*ND1 + d)*32 + c], v);
}

extern "C" void kernel_launch(void* const* d_in, const int* in_sizes, int n_in,
                              void* d_out, int out_size, void* d_ws, size_t ws_size,
                              hipStream_t stream) {
    const float* x        = (const float*)d_in[0];
    const int*   n_id0    = (const int*)d_in[1];
    const int*   res0     = (const int*)d_in[2];
    const int*   esrc0    = (const int*)d_in[3];
    const int*   edst0    = (const int*)d_in[4];
    const int*   res1     = (const int*)d_in[5];
    const int*   esrc1    = (const int*)d_in[6];
    const int*   edst1    = (const int*)d_in[7];
    const float* W1       = (const float*)d_in[8];
    const float* a_src1   = (const float*)d_in[9];
    const float* a_dst1   = (const float*)d_in[10];
    const float* b1       = (const float*)d_in[11];
    const float* W2       = (const float*)d_in[12];
    const float* a_src2   = (const float*)d_in[13];
    const float* a_dst2   = (const float*)d_in[14];
    const float* b2       = (const float*)d_in[15];
    float* outp = (float*)d_out;

    float* ws = (float*)d_ws;
    float* ht1  = ws;                      // NB*NS0*64   = 7,680,000
    float* es1  = ht1 + (size_t)NB*NS0*64; // NB*NS0*8    =   960,000
    float* ed1  = es1 + (size_t)NB*NS0*8;  //             =   960,000
    float* den1 = ed1 + (size_t)NB*NS0*8;  // NB*ND0*8    =   480,000
    float* agg1 = den1 + (size_t)NB*ND0*8; // NB*ND0*64   = 3,840,000
    float* ht2  = agg1 + (size_t)NB*ND0*64;// NB*ND0*32   = 1,920,000
    float* es2  = ht2 + (size_t)NB*ND0*32; // NB*ND0      =    60,000
    float* ed2  = es2 + (size_t)NB*ND0;    //             =    60,000
    float* den2 = ed2 + (size_t)NB*ND0;    // NB*ND1      =    30,000
    // total ~63.96 MB

    k0_init<<<4096, 256, 0, stream>>>(den1, den2, agg1, outp, b1, b2);
    k1_node1<<<(NB*NS0 + 3)/4, 256, 0, stream>>>(x, n_id0, W1, a_src1, a_dst1, ht1, es1, ed1);
    k2_den1<<<(NE0*32 + 255)/256, 256, 0, stream>>>(esrc0, edst0, res0, es1, ed1, den1);
    k3_scat1<<<(NE0*4*64)/256, 256, 0, stream>>>(esrc0, edst0, res0, es1, ed1, den1, ht1, agg1);
    k4_elu<<<(NB*ND0*64 + 255)/256, 256, 0, stream>>>(agg1);
    k5_node2<<<(NB*ND0)/8, 256, 0, stream>>>(agg1, W2, a_src2, a_dst2, ht2, es2, ed2);
    k6_den2<<<(NE1*4 + 255)/256, 256, 0, stream>>>(esrc1, edst1, res1, es2, ed2, den2);
    k7_scat2<<<(NE1*4*32)/256, 256, 0, stream>>>(esrc1, edst1, res1, es2, ed2, den2, ht2, outp);
}

// Round 3
// 438.731 us; speedup vs baseline: 1.8290x; 1.8290x over previous
//
#include <hip/hip_runtime.h>
#include <hip/hip_bf16.h>

#define NB 4
#define NT 40000
#define NS0 30000
#define ND0 15000
#define NE0 360000
#define ND1 7500
#define NE1 180000
#define DIN 64
#define NEG 0.2f

// ---------------- zero degree histograms -----------------------------------
__global__ void kz_zero(int* __restrict__ deg0, int* __restrict__ deg1) {
    int t = blockIdx.x * blockDim.x + threadIdx.x;
    if (t < ND0) deg0[t] = 0;
    if (t < ND1) deg1[t] = 0;
}

// ---------------- histogram of edge destinations ---------------------------
__global__ void kh_hist(const int* __restrict__ edst0, const int* __restrict__ edst1,
                        int* __restrict__ deg0, int* __restrict__ deg1) {
    int t = blockIdx.x * blockDim.x + threadIdx.x;
    if (t < NE0) atomicAdd(&deg0[edst0[t]], 1);
    else if (t < NE0 + NE1) atomicAdd(&deg1[edst1[t - NE0]], 1);
}

// ---------------- exclusive scan (one block per layer) ---------------------
__device__ void scan_block(const int* __restrict__ deg, int* __restrict__ off,
                           int* __restrict__ cur, int n) {
    __shared__ int s[1024];
    int t = threadIdx.x;
    int chunk = (n + 1023) / 1024;
    int base = t * chunk;
    int mysum = 0;
    for (int i = 0; i < chunk; ++i) {
        int idx = base + i;
        if (idx < n) mysum += deg[idx];
    }
    s[t] = mysum;
    __syncthreads();
    for (int o = 1; o < 1024; o <<= 1) {
        int v = (t >= o) ? s[t - o] : 0;
        __syncthreads();
        s[t] += v;
        __syncthreads();
    }
    int run = s[t] - mysum;   // exclusive prefix of my chunk
    for (int i = 0; i < chunk; ++i) {
        int idx = base + i;
        if (idx < n) {
            off[idx] = run;
            cur[idx] = run;
            run += deg[idx];
        }
    }
}

__global__ void ks_scan(const int* __restrict__ deg0, int* __restrict__ off0, int* __restrict__ cur0,
                        const int* __restrict__ deg1, int* __restrict__ off1, int* __restrict__ cur1) {
    if (blockIdx.x == 0) scan_block(deg0, off0, cur0, ND0);
    else                 scan_block(deg1, off1, cur1, ND1);
}

// ---------------- scatter src ids into dst-sorted order --------------------
__global__ void kc_scatter(const int* __restrict__ esrc0, const int* __restrict__ edst0,
                           const int* __restrict__ esrc1, const int* __restrict__ edst1,
                           int* __restrict__ cur0, int* __restrict__ cur1,
                           int* __restrict__ srcsort0, int* __restrict__ srcsort1) {
    int t = blockIdx.x * blockDim.x + threadIdx.x;
    if (t < NE0) {
        int pos = atomicAdd(&cur0[edst0[t]], 1);
        srcsort0[pos] = esrc0[t];
    } else if (t < NE0 + NE1) {
        int e = t - NE0;
        int pos = atomicAdd(&cur1[edst1[e]], 1);
        srcsort1[pos] = esrc1[e];
    }
}

// ---------------- layer 1 node transform: ht1 = x[n_id0] @ W1, es1, ed1 ----
__global__ __launch_bounds__(256) void k1_node1(
        const float* __restrict__ x, const int* __restrict__ n_id0,
        const float* __restrict__ W1, const float* __restrict__ a_src,
        const float* __restrict__ a_dst,
        float* __restrict__ ht1, float* __restrict__ es1, float* __restrict__ ed1) {
    __shared__ float Wl[64*64];
    __shared__ float asl[64], adl[64];
    for (int i = threadIdx.x; i < 64*64; i += 256) Wl[i] = W1[i];
    if (threadIdx.x < 64) { asl[threadIdx.x] = a_src[threadIdx.x]; adl[threadIdx.x] = a_dst[threadIdx.x]; }
    __syncthreads();
    int lane = threadIdx.x & 63;
    int wave = threadIdx.x >> 6;
    int row = blockIdx.x * 4 + wave;          // row in [0, NB*NS0)
    if (row >= NB*NS0) return;
    int b = row / NS0;
    int n = row - b * NS0;
    int id = n_id0[n];
    float xv = x[((size_t)b*NT + id)*DIN + lane];
    float acc = 0.f;
    #pragma unroll
    for (int k = 0; k < 64; ++k) {
        float xk = __shfl(xv, k);
        acc = fmaf(xk, Wl[k*64 + lane], acc);
    }
    ht1[(size_t)row*64 + lane] = acc;
    float vs = acc * asl[lane];
    float vd = acc * adl[lane];
    vs += __shfl_xor(vs, 1); vs += __shfl_xor(vs, 2); vs += __shfl_xor(vs, 4);
    vd += __shfl_xor(vd, 1); vd += __shfl_xor(vd, 2); vd += __shfl_xor(vd, 4);
    if ((lane & 7) == 0) {
        es1[row*8 + (lane >> 3)] = vs;
        ed1[row*8 + (lane >> 3)] = vd;
    }
}

// ---------------- layer 1 per-destination aggregation (fused softmax+ELU) --
// one block per dst d; 4 waves = 4 batches; wave computes 64 output channels
__global__ __launch_bounds__(256) void k3_agg1(
        const int* __restrict__ srcsort0, const int* __restrict__ off0,
        const int* __restrict__ deg0, const int* __restrict__ res0,
        const float* __restrict__ es1, const float* __restrict__ ed1,
        const float* __restrict__ ht1, const float* __restrict__ b1,
        float* __restrict__ agg1) {
    int d = blockIdx.x;
    int b = threadIdx.x >> 6;
    int lane = threadIdx.x & 63;
    int h = lane >> 3;
    int dn = res0[d];
    float edv = ed1[(b*NS0 + dn)*8 + h];
    int start = off0[d];
    int cnt = deg0[d];
    float acc0 = 0.f, acc1 = 0.f, ws0 = 0.f, ws1 = 0.f;
    int i = 0;
    for (; i + 1 < cnt; i += 2) {
        int s0 = srcsort0[start + i];
        int s1 = srcsort0[start + i + 1];
        float e0 = es1[(b*NS0 + s0)*8 + h] + edv;
        float e1 = es1[(b*NS0 + s1)*8 + h] + edv;
        float h0 = ht1[((size_t)(b*NS0 + s0))*64 + lane];
        float h1 = ht1[((size_t)(b*NS0 + s1))*64 + lane];
        e0 = e0 > 0.f ? e0 : NEG * e0;
        e1 = e1 > 0.f ? e1 : NEG * e1;
        float w0 = __expf(e0), w1 = __expf(e1);
        acc0 = fmaf(w0, h0, acc0); ws0 += w0;
        acc1 = fmaf(w1, h1, acc1); ws1 += w1;
    }
    if (i < cnt) {
        int s0 = srcsort0[start + i];
        float e0 = es1[(b*NS0 + s0)*8 + h] + edv;
        float h0 = ht1[((size_t)(b*NS0 + s0))*64 + lane];
        e0 = e0 > 0.f ? e0 : NEG * e0;
        float w0 = __expf(e0);
        acc0 = fmaf(w0, h0, acc0); ws0 += w0;
    }
    float acc = acc0 + acc1, wsum = ws0 + ws1;
    float out = cnt > 0 ? acc / wsum : 0.f;
    out += b1[lane];
    out = out > 0.f ? out : __expf(out) - 1.f;   // fused ELU
    agg1[((size_t)(b*ND0 + d))*64 + lane] = out;
}

// ---------------- layer 2 node transform: ht2 = h @ W2, es2, ed2 -----------
__global__ __launch_bounds__(256) void k5_node2(
        const float* __restrict__ h, const float* __restrict__ W2,
        const float* __restrict__ a_src2, const float* __restrict__ a_dst2,
        float* __restrict__ ht2, float* __restrict__ es2, float* __restrict__ ed2) {
    __shared__ float Wl[64*32];
    __shared__ float hl[8][64];
    __shared__ float as2[32], ad2[32];
    for (int i = threadIdx.x; i < 64*32; i += 256) Wl[i] = W2[i];
    if (threadIdx.x < 32) { as2[threadIdx.x] = a_src2[threadIdx.x]; ad2[threadIdx.x] = a_dst2[threadIdx.x]; }
    __syncthreads();
    int base = blockIdx.x * 8;                 // rows total NB*ND0 = 60000 (div by 8)
    for (int i = threadIdx.x; i < 512; i += 256) {
        int r = i >> 6, k = i & 63;
        hl[r][k] = h[(size_t)(base + r)*64 + k];
    }
    __syncthreads();
    int r = threadIdx.x >> 5, c = threadIdx.x & 31;
    float acc = 0.f;
    #pragma unroll
    for (int k = 0; k < 64; ++k) acc = fmaf(hl[r][k], Wl[k*32 + c], acc);
    int row = base + r;
    ht2[(size_t)row*32 + c] = acc;
    float vs = acc * as2[c], vd = acc * ad2[c];
    vs += __shfl_xor(vs, 1); vs += __shfl_xor(vs, 2); vs += __shfl_xor(vs, 4);
    vs += __shfl_xor(vs, 8); vs += __shfl_xor(vs, 16);
    vd += __shfl_xor(vd, 1); vd += __shfl_xor(vd, 2); vd += __shfl_xor(vd, 4);
    vd += __shfl_xor(vd, 8); vd += __shfl_xor(vd, 16);
    if (c == 0) { es2[row] = vs; ed2[row] = vd; }
}

// ---------------- layer 2 per-destination aggregation ----------------------
// one block per dst d; 4 waves = 4 batches; each wave: 2 edges/iter (C=32)
__global__ __launch_bounds__(256) void k7_agg2(
        const int* __restrict__ srcsort1, const int* __restrict__ off1,
        const int* __restrict__ deg1, const int* __restrict__ res1,
        const float* __restrict__ es2, const float* __restrict__ ed2,
        const float* __restrict__ ht2, const float* __restrict__ b2,
        float* __restrict__ outp) {
    int d = blockIdx.x;
    int b = threadIdx.x >> 6;
    int lane = threadIdx.x & 63;
    int grp = lane >> 5;
    int c = lane & 31;
    int dn = res1[d];
    float edv = ed2[b*ND0 + dn];
    int start = off1[d];
    int cnt = deg1[d];
    float acc = 0.f, wsum = 0.f;
    for (int i = grp; i < cnt; i += 2) {
        int s = srcsort1[start + i];
        float lg = es2[b*ND0 + s] + edv;
        lg = lg > 0.f ? lg : NEG * lg;
        float w = __expf(lg);
        float hv = ht2[((size_t)(b*ND0 + s))*32 + c];
        acc = fmaf(w, hv, acc);
        wsum += w;
    }
    acc  += __shfl_xor(acc, 32);
    wsum += __shfl_xor(wsum, 32);
    float out = cnt > 0 ? acc / wsum : 0.f;
    out += b2[c];
    if (grp == 0) outp[((size_t)(b*ND1 + d))*32 + c] = out;
}

extern "C" void kernel_launch(void* const* d_in, const int* in_sizes, int n_in,
                              void* d_out, int out_size, void* d_ws, size_t ws_size,
                              hipStream_t stream) {
    const float* x        = (const float*)d_in[0];
    const int*   n_id0    = (const int*)d_in[1];
    const int*   res0     = (const int*)d_in[2];
    const int*   esrc0    = (const int*)d_in[3];
    const int*   edst0    = (const int*)d_in[4];
    const int*   res1     = (const int*)d_in[5];
    const int*   esrc1    = (const int*)d_in[6];
    const int*   edst1    = (const int*)d_in[7];
    const float* W1       = (const float*)d_in[8];
    const float* a_src1   = (const float*)d_in[9];
    const float* a_dst1   = (const float*)d_in[10];
    const float* b1       = (const float*)d_in[11];
    const float* W2       = (const float*)d_in[12];
    const float* a_src2   = (const float*)d_in[13];
    const float* a_dst2   = (const float*)d_in[14];
    const float* b2       = (const float*)d_in[15];
    float* outp = (float*)d_out;

    float* ws = (float*)d_ws;
    float* ht1  = ws;                        // NB*NS0*64   = 7,680,000 f
    float* es1  = ht1 + (size_t)NB*NS0*64;   // NB*NS0*8    =   960,000 f
    float* ed1  = es1 + (size_t)NB*NS0*8;    //             =   960,000 f
    float* agg1 = ed1 + (size_t)NB*NS0*8;    // NB*ND0*64   = 3,840,000 f
    // ht2/es2/ed2 alias the (dead-by-then) ht1 region
    float* ht2  = ht1;                       // NB*ND0*32   = 1,920,000 f (< ht1)
    float* es2  = ht2 + (size_t)NB*ND0*32;   // NB*ND0      =    60,000 f
    float* ed2  = es2 + (size_t)NB*ND0;      //             =    60,000 f
    int* ip = (int*)(agg1 + (size_t)NB*ND0*64);
    int* deg0     = ip;                      // 15000
    int* off0     = deg0 + ND0;              // 15000
    int* cur0     = off0 + ND0;              // 15000
    int* deg1     = cur0 + ND0;              // 7500
    int* off1     = deg1 + ND1;              // 7500
    int* cur1     = off1 + ND1;              // 7500
    int* srcsort0 = cur1 + ND1;              // 360000
    int* srcsort1 = srcsort0 + NE0;          // 180000
    // total ~56.2 MB

    kz_zero<<<(ND0 + 255)/256, 256, 0, stream>>>(deg0, deg1);
    kh_hist<<<(NE0 + NE1 + 255)/256, 256, 0, stream>>>(edst0, edst1, deg0, deg1);
    ks_scan<<<2, 1024, 0, stream>>>(deg0, off0, cur0, deg1, off1, cur1);
    kc_scatter<<<(NE0 + NE1 + 255)/256, 256, 0, stream>>>(esrc0, edst0, esrc1, edst1,
                                                          cur0, cur1, srcsort0, srcsort1);
    k1_node1<<<(NB*NS0)/4, 256, 0, stream>>>(x, n_id0, W1, a_src1, a_dst1, ht1, es1, ed1);
    k3_agg1<<<ND0, 256, 0, stream>>>(srcsort0, off0, deg0, res0, es1, ed1, ht1, b1, agg1);
    k5_node2<<<(NB*ND0)/8, 256, 0, stream>>>(agg1, W2, a_src2, a_dst2, ht2, es2, ed2);
    k7_agg2<<<ND1, 256, 0, stream>>>(srcsort1, off1, deg1, res1, es2, ed2, ht2, b2, outp);
}

// Round 4
// 328.251 us; speedup vs baseline: 2.4447x; 1.3366x over previous
//
#include <hip/hip_runtime.h>
#include <hip/hip_bf16.h>

#define NB 4
#define NT 40000
#define NS0 30000
#define ND0 15000
#define NE0 360000
#define ND1 7500
#define NE1 180000
#define DIN 64
#define NEG 0.2f

// ---------------- zero degree histograms -----------------------------------
__global__ void kz_zero(int* __restrict__ deg0, int* __restrict__ deg1) {
    int t = blockIdx.x * blockDim.x + threadIdx.x;
    if (t < ND0) deg0[t] = 0;
    if (t < ND1) deg1[t] = 0;
}

// ---------------- histogram of edge destinations ---------------------------
__global__ void kh_hist(const int* __restrict__ edst0, const int* __restrict__ edst1,
                        int* __restrict__ deg0, int* __restrict__ deg1) {
    int t = blockIdx.x * blockDim.x + threadIdx.x;
    if (t < NE0) atomicAdd(&deg0[edst0[t]], 1);
    else if (t < NE0 + NE1) atomicAdd(&deg1[edst1[t - NE0]], 1);
}

// ---------------- exclusive scan (one block per layer) ---------------------
__device__ void scan_block(const int* __restrict__ deg, int* __restrict__ off,
                           int* __restrict__ cur, int n) {
    __shared__ int s[1024];
    int t = threadIdx.x;
    int chunk = (n + 1023) / 1024;
    int base = t * chunk;
    int mysum = 0;
    for (int i = 0; i < chunk; ++i) {
        int idx = base + i;
        if (idx < n) mysum += deg[idx];
    }
    s[t] = mysum;
    __syncthreads();
    for (int o = 1; o < 1024; o <<= 1) {
        int v = (t >= o) ? s[t - o] : 0;
        __syncthreads();
        s[t] += v;
        __syncthreads();
    }
    int run = s[t] - mysum;   // exclusive prefix of my chunk
    for (int i = 0; i < chunk; ++i) {
        int idx = base + i;
        if (idx < n) {
            off[idx] = run;
            cur[idx] = run;
            run += deg[idx];
        }
    }
}

__global__ void ks_scan(const int* __restrict__ deg0, int* __restrict__ off0, int* __restrict__ cur0,
                        const int* __restrict__ deg1, int* __restrict__ off1, int* __restrict__ cur1) {
    if (blockIdx.x == 0) scan_block(deg0, off0, cur0, ND0);
    else                 scan_block(deg1, off1, cur1, ND1);
}

// ---------------- scatter src ids into dst-sorted order --------------------
__global__ void kc_scatter(const int* __restrict__ esrc0, const int* __restrict__ edst0,
                           const int* __restrict__ esrc1, const int* __restrict__ edst1,
                           int* __restrict__ cur0, int* __restrict__ cur1,
                           int* __restrict__ srcsort0, int* __restrict__ srcsort1) {
    int t = blockIdx.x * blockDim.x + threadIdx.x;
    if (t < NE0) {
        int pos = atomicAdd(&cur0[edst0[t]], 1);
        srcsort0[pos] = esrc0[t];
    } else if (t < NE0 + NE1) {
        int e = t - NE0;
        int pos = atomicAdd(&cur1[edst1[e]], 1);
        srcsort1[pos] = esrc1[e];
    }
}

// ---------------- layer 1 node transform (register-blocked GEMM) -----------
// tile: 64 rows x 64 cols, thread = 4x4; xt transposed [k][row] pad 68
__global__ __launch_bounds__(256) void k1_node1(
        const float* __restrict__ x, const int* __restrict__ n_id0,
        const float* __restrict__ W1, const float* __restrict__ a_src,
        const float* __restrict__ a_dst,
        float* __restrict__ ht1, float* __restrict__ es1, float* __restrict__ ed1) {
    __shared__ float xt[64*68];
    __shared__ float Wl[64*64];
    __shared__ float asl[64], adl[64];
    int t = threadIdx.x;
    for (int i = t; i < 1024; i += 256)
        *(float4*)&Wl[i*4] = *(const float4*)&W1[i*4];
    if (t < 64) { asl[t] = a_src[t]; adl[t] = a_dst[t]; }
    // stage 64 gathered rows, transposed
    int rr = t & 63;
    int q  = t >> 6;                       // k-quarter 0..3
    int row_s = blockIdx.x * 64 + rr;      // < 120000 always (1875*64)
    int bs = row_s / NS0;
    int ns = row_s - bs * NS0;
    const float* xrow = x + ((size_t)(bs * NT + n_id0[ns])) * 64;
    #pragma unroll
    for (int j = 0; j < 4; ++j) {
        int k = q * 16 + j * 4;
        float4 v = *(const float4*)&xrow[k];
        xt[(k+0)*68 + rr] = v.x;
        xt[(k+1)*68 + rr] = v.y;
        xt[(k+2)*68 + rr] = v.z;
        xt[(k+3)*68 + rr] = v.w;
    }
    __syncthreads();
    int c0 = (t & 15) * 4;                 // col group (wave-local reduction partner = lane^1)
    int r0 = (t >> 4) * 4;
    float acc[4][4] = {};
    #pragma unroll 16
    for (int k = 0; k < 64; ++k) {
        float4 a = *(const float4*)&xt[k*68 + r0];
        float4 w = *(const float4*)&Wl[k*64 + c0];
        acc[0][0] = fmaf(a.x, w.x, acc[0][0]); acc[0][1] = fmaf(a.x, w.y, acc[0][1]);
        acc[0][2] = fmaf(a.x, w.z, acc[0][2]); acc[0][3] = fmaf(a.x, w.w, acc[0][3]);
        acc[1][0] = fmaf(a.y, w.x, acc[1][0]); acc[1][1] = fmaf(a.y, w.y, acc[1][1]);
        acc[1][2] = fmaf(a.y, w.z, acc[1][2]); acc[1][3] = fmaf(a.y, w.w, acc[1][3]);
        acc[2][0] = fmaf(a.z, w.x, acc[2][0]); acc[2][1] = fmaf(a.z, w.y, acc[2][1]);
        acc[2][2] = fmaf(a.z, w.z, acc[2][2]); acc[2][3] = fmaf(a.z, w.w, acc[2][3]);
        acc[3][0] = fmaf(a.w, w.x, acc[3][0]); acc[3][1] = fmaf(a.w, w.y, acc[3][1]);
        acc[3][2] = fmaf(a.w, w.z, acc[3][2]); acc[3][3] = fmaf(a.w, w.w, acc[3][3]);
    }
    float as0 = asl[c0], as1 = asl[c0+1], as2 = asl[c0+2], as3 = asl[c0+3];
    float ad0 = adl[c0], ad1 = adl[c0+1], ad2 = adl[c0+2], ad3 = adl[c0+3];
    int hh = (t & 15) >> 1;                // head index for even lanes
    #pragma unroll
    for (int i = 0; i < 4; ++i) {
        int row = blockIdx.x * 64 + r0 + i;
        float4 o = make_float4(acc[i][0], acc[i][1], acc[i][2], acc[i][3]);
        *(float4*)&ht1[(size_t)row*64 + c0] = o;
        float ps = acc[i][0]*as0 + acc[i][1]*as1 + acc[i][2]*as2 + acc[i][3]*as3;
        float pd = acc[i][0]*ad0 + acc[i][1]*ad1 + acc[i][2]*ad2 + acc[i][3]*ad3;
        ps += __shfl_xor(ps, 1);
        pd += __shfl_xor(pd, 1);
        if ((t & 1) == 0) {
            es1[row*8 + hh] = ps;
            ed1[row*8 + hh] = pd;
        }
    }
}

// ---------------- layer 1 per-destination aggregation (fused softmax+ELU) --
__global__ __launch_bounds__(256) void k3_agg1(
        const int* __restrict__ srcsort0, const int* __restrict__ off0,
        const int* __restrict__ deg0, const int* __restrict__ res0,
        const float* __restrict__ es1, const float* __restrict__ ed1,
        const float* __restrict__ ht1, const float* __restrict__ b1,
        float* __restrict__ agg1) {
    int d = blockIdx.x;
    int b = threadIdx.x >> 6;
    int lane = threadIdx.x & 63;
    int h = lane >> 3;
    int dn = res0[d];
    float edv = ed1[(b*NS0 + dn)*8 + h];
    int start = off0[d];
    int cnt = deg0[d];
    float acc0 = 0.f, acc1 = 0.f, ws0 = 0.f, ws1 = 0.f;
    int i = 0;
    for (; i + 1 < cnt; i += 2) {
        int s0 = srcsort0[start + i];
        int s1 = srcsort0[start + i + 1];
        float e0 = es1[(b*NS0 + s0)*8 + h] + edv;
        float e1 = es1[(b*NS0 + s1)*8 + h] + edv;
        float h0 = ht1[((size_t)(b*NS0 + s0))*64 + lane];
        float h1 = ht1[((size_t)(b*NS0 + s1))*64 + lane];
        e0 = e0 > 0.f ? e0 : NEG * e0;
        e1 = e1 > 0.f ? e1 : NEG * e1;
        float w0 = __expf(e0), w1 = __expf(e1);
        acc0 = fmaf(w0, h0, acc0); ws0 += w0;
        acc1 = fmaf(w1, h1, acc1); ws1 += w1;
    }
    if (i < cnt) {
        int s0 = srcsort0[start + i];
        float e0 = es1[(b*NS0 + s0)*8 + h] + edv;
        float h0 = ht1[((size_t)(b*NS0 + s0))*64 + lane];
        e0 = e0 > 0.f ? e0 : NEG * e0;
        float w0 = __expf(e0);
        acc0 = fmaf(w0, h0, acc0); ws0 += w0;
    }
    float acc = acc0 + acc1, wsum = ws0 + ws1;
    float out = cnt > 0 ? acc / wsum : 0.f;
    out += b1[lane];
    out = out > 0.f ? out : __expf(out) - 1.f;   // fused ELU
    agg1[((size_t)(b*ND0 + d))*64 + lane] = out;
}

// ---------------- layer 2 node transform (register-blocked GEMM) -----------
// tile: 128 rows x 32 cols, thread = 4x4; xt transposed [k][row] pad 132
__global__ __launch_bounds__(256) void k5_node2(
        const float* __restrict__ h, const float* __restrict__ W2,
        const float* __restrict__ a_src2, const float* __restrict__ a_dst2,
        float* __restrict__ ht2, float* __restrict__ es2, float* __restrict__ ed2) {
    __shared__ float xt[64*132];
    __shared__ float Wl[64*32];
    __shared__ float as2[32], ad2[32];
    int t = threadIdx.x;
    for (int i = t; i < 512; i += 256)
        *(float4*)&Wl[i*4] = *(const float4*)&W2[i*4];
    if (t < 32) { as2[t] = a_src2[t]; ad2[t] = a_dst2[t]; }
    int rr = t & 127;
    int q  = t >> 7;                        // k-half 0..1
    int row_s = blockIdx.x * 128 + rr;
    bool valid = row_s < NB*ND0;
    const float* hrow = h + (size_t)row_s * 64;
    #pragma unroll
    for (int j = 0; j < 8; ++j) {
        int k = q * 32 + j * 4;
        float4 v = valid ? *(const float4*)&hrow[k] : make_float4(0.f,0.f,0.f,0.f);
        xt[(k+0)*132 + rr] = v.x;
        xt[(k+1)*132 + rr] = v.y;
        xt[(k+2)*132 + rr] = v.z;
        xt[(k+3)*132 + rr] = v.w;
    }
    __syncthreads();
    int c0 = (t & 7) * 4;                   // reduction partners lane^{1,2,4}
    int r0 = (t >> 3) * 4;
    float acc[4][4] = {};
    #pragma unroll 16
    for (int k = 0; k < 64; ++k) {
        float4 a = *(const float4*)&xt[k*132 + r0];
        float4 w = *(const float4*)&Wl[k*32 + c0];
        acc[0][0] = fmaf(a.x, w.x, acc[0][0]); acc[0][1] = fmaf(a.x, w.y, acc[0][1]);
        acc[0][2] = fmaf(a.x, w.z, acc[0][2]); acc[0][3] = fmaf(a.x, w.w, acc[0][3]);
        acc[1][0] = fmaf(a.y, w.x, acc[1][0]); acc[1][1] = fmaf(a.y, w.y, acc[1][1]);
        acc[1][2] = fmaf(a.y, w.z, acc[1][2]); acc[1][3] = fmaf(a.y, w.w, acc[1][3]);
        acc[2][0] = fmaf(a.z, w.x, acc[2][0]); acc[2][1] = fmaf(a.z, w.y, acc[2][1]);
        acc[2][2] = fmaf(a.z, w.z, acc[2][2]); acc[2][3] = fmaf(a.z, w.w, acc[2][3]);
        acc[3][0] = fmaf(a.w, w.x, acc[3][0]); acc[3][1] = fmaf(a.w, w.y, acc[3][1]);
        acc[3][2] = fmaf(a.w, w.z, acc[3][2]); acc[3][3] = fmaf(a.w, w.w, acc[3][3]);
    }
    float s0 = as2[c0], s1 = as2[c0+1], s2 = as2[c0+2], s3 = as2[c0+3];
    float d0 = ad2[c0], d1 = ad2[c0+1], d2 = ad2[c0+2], d3 = ad2[c0+3];
    #pragma unroll
    for (int i = 0; i < 4; ++i) {
        int row = blockIdx.x * 128 + r0 + i;
        float ps = acc[i][0]*s0 + acc[i][1]*s1 + acc[i][2]*s2 + acc[i][3]*s3;
        float pd = acc[i][0]*d0 + acc[i][1]*d1 + acc[i][2]*d2 + acc[i][3]*d3;
        ps += __shfl_xor(ps, 1); ps += __shfl_xor(ps, 2); ps += __shfl_xor(ps, 4);
        pd += __shfl_xor(pd, 1); pd += __shfl_xor(pd, 2); pd += __shfl_xor(pd, 4);
        if (row < NB*ND0) {
            *(float4*)&ht2[(size_t)row*32 + c0] =
                make_float4(acc[i][0], acc[i][1], acc[i][2], acc[i][3]);
            if ((t & 7) == 0) { es2[row] = ps; ed2[row] = pd; }
        }
    }
}

// ---------------- layer 2 per-destination aggregation ----------------------
__global__ __launch_bounds__(256) void k7_agg2(
        const int* __restrict__ srcsort1, const int* __restrict__ off1,
        const int* __restrict__ deg1, const int* __restrict__ res1,
        const float* __restrict__ es2, const float* __restrict__ ed2,
        const float* __restrict__ ht2, const float* __restrict__ b2,
        float* __restrict__ outp) {
    int d = blockIdx.x;
    int b = threadIdx.x >> 6;
    int lane = threadIdx.x & 63;
    int grp = lane >> 5;
    int c = lane & 31;
    int dn = res1[d];
    float edv = ed2[b*ND0 + dn];
    int start = off1[d];
    int cnt = deg1[d];
    float acc = 0.f, wsum = 0.f;
    for (int i = grp; i < cnt; i += 2) {
        int s = srcsort1[start + i];
        float lg = es2[b*ND0 + s] + edv;
        lg = lg > 0.f ? lg : NEG * lg;
        float w = __expf(lg);
        float hv = ht2[((size_t)(b*ND0 + s))*32 + c];
        acc = fmaf(w, hv, acc);
        wsum += w;
    }
    acc  += __shfl_xor(acc, 32);
    wsum += __shfl_xor(wsum, 32);
    float out = cnt > 0 ? acc / wsum : 0.f;
    out += b2[c];
    if (grp == 0) outp[((size_t)(b*ND1 + d))*32 + c] = out;
}

extern "C" void kernel_launch(void* const* d_in, const int* in_sizes, int n_in,
                              void* d_out, int out_size, void* d_ws, size_t ws_size,
                              hipStream_t stream) {
    const float* x        = (const float*)d_in[0];
    const int*   n_id0    = (const int*)d_in[1];
    const int*   res0     = (const int*)d_in[2];
    const int*   esrc0    = (const int*)d_in[3];
    const int*   edst0    = (const int*)d_in[4];
    const int*   res1     = (const int*)d_in[5];
    const int*   esrc1    = (const int*)d_in[6];
    const int*   edst1    = (const int*)d_in[7];
    const float* W1       = (const float*)d_in[8];
    const float* a_src1   = (const float*)d_in[9];
    const float* a_dst1   = (const float*)d_in[10];
    const float* b1       = (const float*)d_in[11];
    const float* W2       = (const float*)d_in[12];
    const float* a_src2   = (const float*)d_in[13];
    const float* a_dst2   = (const float*)d_in[14];
    const float* b2       = (const float*)d_in[15];
    float* outp = (float*)d_out;

    float* ws = (float*)d_ws;
    float* ht1  = ws;                        // NB*NS0*64   = 7,680,000 f
    float* es1  = ht1 + (size_t)NB*NS0*64;   // NB*NS0*8    =   960,000 f
    float* ed1  = es1 + (size_t)NB*NS0*8;    //             =   960,000 f
    float* agg1 = ed1 + (size_t)NB*NS0*8;    // NB*ND0*64   = 3,840,000 f
    // ht2/es2/ed2 alias the (dead-by-then) ht1 region
    float* ht2  = ht1;                       // NB*ND0*32   = 1,920,000 f (< ht1)
    float* es2  = ht2 + (size_t)NB*ND0*32;   // NB*ND0      =    60,000 f
    float* ed2  = es2 + (size_t)NB*ND0;      //             =    60,000 f
    int* ip = (int*)(agg1 + (size_t)NB*ND0*64);
    int* deg0     = ip;                      // 15000
    int* off0     = deg0 + ND0;              // 15000
    int* cur0     = off0 + ND0;              // 15000
    int* deg1     = cur0 + ND0;              // 7500
    int* off1     = deg1 + ND1;              // 7500
    int* cur1     = off1 + ND1;              // 7500
    int* srcsort0 = cur1 + ND1;              // 360000
    int* srcsort1 = srcsort0 + NE0;          // 180000
    // total ~56.2 MB

    kz_zero<<<(ND0 + 255)/256, 256, 0, stream>>>(deg0, deg1);
    kh_hist<<<(NE0 + NE1 + 255)/256, 256, 0, stream>>>(edst0, edst1, deg0, deg1);
    ks_scan<<<2, 1024, 0, stream>>>(deg0, off0, cur0, deg1, off1, cur1);
    kc_scatter<<<(NE0 + NE1 + 255)/256, 256, 0, stream>>>(esrc0, edst0, esrc1, edst1,
                                                          cur0, cur1, srcsort0, srcsort1);
    k1_node1<<<(NB*NS0)/64, 256, 0, stream>>>(x, n_id0, W1, a_src1, a_dst1, ht1, es1, ed1);
    k3_agg1<<<ND0, 256, 0, stream>>>(srcsort0, off0, deg0, res0, es1, ed1, ht1, b1, agg1);
    k5_node2<<<(NB*ND0 + 127)/128, 256, 0, stream>>>(agg1, W2, a_src2, a_dst2, ht2, es2, ed2);
    k7_agg2<<<ND1, 256, 0, stream>>>(srcsort1, off1, deg1, res1, es2, ed2, ht2, b2, outp);
}